// Round 3
// baseline (4132.946 us; speedup 1.0000x reference)
//
#include <hip/hip_runtime.h>
#include <hip/hip_bf16.h>

// Problem constants (shapes fixed by the reference; N/E/BN derived at launch)
constexpr int G4H   = 128;  // 4*H
constexpr int FH    = 96;   // F+H
constexpr int F_DIM = 64;
constexpr int H_DIM = 32;
constexpr int TILE  = 8;    // nodes per inner tile in GEMM
constexpr int NPB   = 64;   // nodes per block in GEMM

static __device__ __forceinline__ float bf2f(__hip_bfloat16 v) { return __bfloat162float(v); }

// ---------------- xw = concat(x,h) @ W  (fp32 in, fp32 accum, bf16 out) ----------------
__global__ __launch_bounds__(128)
void xw_kernel(const float* __restrict__ x,
               const float* __restrict__ h,
               const float* __restrict__ W,
               __hip_bfloat16* __restrict__ xw,
               long BN)
{
    __shared__ float Wl[FH * G4H];     // [f][g] — same layout as W
    __shared__ float comb[TILE * FH];  // [i][f]
    const int g = threadIdx.x;         // 0..127 → output column

    for (int idx = g; idx < FH * G4H; idx += 128) Wl[idx] = W[idx];
    __syncthreads();

    const long base = (long)blockIdx.x * NPB;
    for (int t = 0; t < NPB; t += TILE) {
        const long bn0 = base + t;
        // cooperative load of TILE nodes' combined [x|h] features
        #pragma unroll
        for (int j = 0; j < (TILE * FH) / 128; ++j) {
            int idx = g + 128 * j;
            int i = idx / FH;
            int f = idx - i * FH;
            long bn = bn0 + i;
            float v = 0.f;
            if (bn < BN)
                v = (f < F_DIM) ? x[bn * F_DIM + f]
                                : h[bn * H_DIM + (f - F_DIM)];
            comb[idx] = v;
        }
        __syncthreads();

        float acc[TILE];
        #pragma unroll
        for (int i = 0; i < TILE; ++i) acc[i] = 0.f;

        #pragma unroll
        for (int f = 0; f < FH; f += 4) {
            float w0 = Wl[(f + 0) * G4H + g];
            float w1 = Wl[(f + 1) * G4H + g];
            float w2 = Wl[(f + 2) * G4H + g];
            float w3 = Wl[(f + 3) * G4H + g];
            #pragma unroll
            for (int i = 0; i < TILE; ++i) {
                const float4 c4 = *reinterpret_cast<const float4*>(&comb[i * FH + f]);
                acc[i] = fmaf(c4.x, w0, fmaf(c4.y, w1, fmaf(c4.z, w2, fmaf(c4.w, w3, acc[i]))));
            }
        }
        #pragma unroll
        for (int i = 0; i < TILE; ++i) {
            long bn = bn0 + i;
            if (bn < BN) xw[bn * G4H + g] = __float2bfloat16(acc[i]);
        }
        __syncthreads();
    }
}

// ---------------- zero scratch (agg + deg) ----------------
__global__ __launch_bounds__(256)
void zero_kernel(uint4* __restrict__ p, long n4)
{
    long i = (long)blockIdx.x * 256 + threadIdx.x;
    if (i < n4) p[i] = make_uint4(0u, 0u, 0u, 0u);
}

// ---------------- degree over dst ----------------
__global__ __launch_bounds__(256)
void deg_kernel(const int* __restrict__ ei, int E, unsigned* __restrict__ deg)
{
    int e = blockIdx.x * 256 + threadIdx.x;
    if (e < E) atomicAdd(&deg[ei[E + e]], 1u);
}

// ---------------- dinv = rsqrt(deg + 1 self-loop) ----------------
__global__ __launch_bounds__(256)
void dinv_kernel(const unsigned* __restrict__ deg, float* __restrict__ dinv, int N)
{
    int n = blockIdx.x * 256 + threadIdx.x;
    if (n < N) dinv[n] = rsqrtf((float)(deg[n] + 1u));
}

// ---------------- edge scatter: one wave per edge, 4 k's per lane ----------------
__global__ __launch_bounds__(256)
void scatter_kernel(const int* __restrict__ ei,
                    const __hip_bfloat16* __restrict__ xw,
                    const float* __restrict__ dinv,
                    float* __restrict__ agg,
                    int E, int N)
{
    long tid = (long)blockIdx.x * 256 + threadIdx.x;
    int e = (int)(tid >> 6);
    if (e >= E) return;
    int lane = (int)(tid & 63);
    int src = ei[e];
    int dst = ei[E + e];
    float nrm = dinv[src] * dinv[dst];
    int b = lane >> 5;            // batch 0/1
    int k = (lane & 31) << 2;     // k in steps of 4
    long sbase = ((long)b * N + src) * G4H + k;
    long dbase = ((long)b * N + dst) * G4H + k;
    uint2 u = *reinterpret_cast<const uint2*>(xw + sbase);
    float v0 = __uint_as_float(u.x << 16);
    float v1 = __uint_as_float(u.x & 0xffff0000u);
    float v2 = __uint_as_float(u.y << 16);
    float v3 = __uint_as_float(u.y & 0xffff0000u);
    float* ad = agg + dbase;
    atomicAdd(ad + 0, v0 * nrm);
    atomicAdd(ad + 1, v1 * nrm);
    atomicAdd(ad + 2, v2 * nrm);
    atomicAdd(ad + 3, v3 * nrm);
}

// ---------------- fused self-loop + bias + LSTM gating + epilogue (fp32 out) ----------------
__global__ __launch_bounds__(256)
void gate_kernel(const float* __restrict__ agg,
                 const __hip_bfloat16* __restrict__ xw,
                 const float* __restrict__ dinv,
                 const float* __restrict__ bias,
                 const float* __restrict__ c_cur,
                 float* __restrict__ out,   // [h_next | c_next] fp32
                 int N, long BN)
{
    long t = (long)blockIdx.x * 256 + threadIdx.x;
    if (t >= BN * H_DIM) return;
    long bn = t >> 5;
    int hh = (int)(t & 31);
    int n = (int)(bn % N);
    float di = dinv[n];
    float selfw = di * di;
    long base = bn * G4H;

    float cc[4];
    #pragma unroll
    for (int j = 0; j < 4; ++j) {
        int k = j * 32 + hh;
        cc[j] = agg[base + k] + bf2f(xw[base + k]) * selfw + bias[k];
    }
    float ig = 1.f / (1.f + __expf(-cc[0]));
    float fg = 1.f / (1.f + __expf(-cc[1]));
    float og = 1.f / (1.f + __expf(-cc[2]));
    float gg = tanhf(cc[3]);
    float c  = c_cur[t];
    float cn = fmaf(fg, c, ig * gg);
    float hn = og * tanhf(cn);
    out[t]              = hn;
    out[BN * H_DIM + t] = cn;
}

extern "C" void kernel_launch(void* const* d_in, const int* in_sizes, int n_in,
                              void* d_out, int out_size, void* d_ws, size_t ws_size,
                              hipStream_t stream)
{
    const float* x    = (const float*)d_in[0];
    const int*   ei   = (const int*)d_in[1];
    const float* h    = (const float*)d_in[2];
    const float* c    = (const float*)d_in[3];
    const float* W    = (const float*)d_in[4];
    const float* bias = (const float*)d_in[5];

    const int  E  = in_sizes[1] / 2;                 // 800000
    const long BN = (long)in_sizes[2] / H_DIM;       // B*N = 100000
    const int  B  = 2;
    const int  N  = (int)(BN / B);                   // 50000

    // workspace layout
    char* ws = (char*)d_ws;
    __hip_bfloat16* xw = (__hip_bfloat16*)ws;                       // BN*128 bf16
    size_t off = (size_t)BN * G4H * sizeof(__hip_bfloat16);
    float* agg = (float*)(ws + off);                                // BN*128 f32
    off += (size_t)BN * G4H * sizeof(float);
    unsigned* deg = (unsigned*)(ws + off);                          // N u32
    off += (size_t)N * sizeof(unsigned);
    float* dinv = (float*)(ws + off);                               // N f32

    // 1) GEMM xw = [x|h] @ W
    int gemm_grid = (int)((BN + NPB - 1) / NPB);
    xw_kernel<<<gemm_grid, 128, 0, stream>>>(x, h, W, xw, BN);

    // 2) zero agg + deg (contiguous regions; overrun into dinv is fine — rewritten)
    long zero_bytes = (long)BN * G4H * 4 + (long)N * 4;
    long n4 = (zero_bytes + 15) / 16;
    zero_kernel<<<(int)((n4 + 255) / 256), 256, 0, stream>>>((uint4*)agg, n4);

    // 3) degree histogram over dst
    deg_kernel<<<(E + 255) / 256, 256, 0, stream>>>(ei, E, deg);

    // 4) dinv = rsqrt(deg+1)
    dinv_kernel<<<(N + 255) / 256, 256, 0, stream>>>(deg, dinv, N);

    // 5) edge scatter (one wave per edge; 204.8M fp32 atomics)
    long sc_threads = (long)E * 64;
    scatter_kernel<<<(int)((sc_threads + 255) / 256), 256, 0, stream>>>(ei, xw, dinv, agg, E, N);

    // 6) fused self-loop + bias + LSTM gates + write h_next|c_next (fp32)
    long gt_threads = BN * H_DIM;
    gate_kernel<<<(int)((gt_threads + 255) / 256), 256, 0, stream>>>(
        agg, xw, dinv, bias, c, (float*)d_out, N, BN);
}

// Round 4
// 1722.291 us; speedup vs baseline: 2.3997x; 2.3997x over previous
//
#include <hip/hip_runtime.h>
#include <hip/hip_bf16.h>

constexpr int G4H   = 128;  // 4*H
constexpr int FH    = 96;   // F+H
constexpr int F_DIM = 64;
constexpr int H_DIM = 32;
constexpr int TILE  = 8;    // nodes per inner tile in GEMM
constexpr int NPB   = 64;   // nodes per block in GEMM

static __device__ __forceinline__ float bf2f(__hip_bfloat16 v) { return __bfloat162float(v); }

// ---------------- xw = concat(x,h) @ W  (fp32 in, fp32 accum, bf16 out) ----------------
__global__ __launch_bounds__(128)
void xw_kernel(const float* __restrict__ x,
               const float* __restrict__ h,
               const float* __restrict__ W,
               __hip_bfloat16* __restrict__ xw,
               long BN)
{
    __shared__ float Wl[FH * G4H];     // [f][g]
    __shared__ float comb[TILE * FH];  // [i][f]
    const int g = threadIdx.x;         // 0..127 → output column

    for (int idx = g; idx < FH * G4H; idx += 128) Wl[idx] = W[idx];
    __syncthreads();

    const long base = (long)blockIdx.x * NPB;
    for (int t = 0; t < NPB; t += TILE) {
        const long bn0 = base + t;
        #pragma unroll
        for (int j = 0; j < (TILE * FH) / 128; ++j) {
            int idx = g + 128 * j;
            int i = idx / FH;
            int f = idx - i * FH;
            long bn = bn0 + i;
            float v = 0.f;
            if (bn < BN)
                v = (f < F_DIM) ? x[bn * F_DIM + f]
                                : h[bn * H_DIM + (f - F_DIM)];
            comb[idx] = v;
        }
        __syncthreads();

        float acc[TILE];
        #pragma unroll
        for (int i = 0; i < TILE; ++i) acc[i] = 0.f;

        #pragma unroll
        for (int f = 0; f < FH; f += 4) {
            float w0 = Wl[(f + 0) * G4H + g];
            float w1 = Wl[(f + 1) * G4H + g];
            float w2 = Wl[(f + 2) * G4H + g];
            float w3 = Wl[(f + 3) * G4H + g];
            #pragma unroll
            for (int i = 0; i < TILE; ++i) {
                const float4 c4 = *reinterpret_cast<const float4*>(&comb[i * FH + f]);
                acc[i] = fmaf(c4.x, w0, fmaf(c4.y, w1, fmaf(c4.z, w2, fmaf(c4.w, w3, acc[i]))));
            }
        }
        #pragma unroll
        for (int i = 0; i < TILE; ++i) {
            long bn = bn0 + i;
            if (bn < BN) xw[bn * G4H + g] = __float2bfloat16(acc[i]);
        }
        __syncthreads();
    }
}

// ---------------- zero deg ----------------
__global__ __launch_bounds__(256)
void zero_deg_kernel(unsigned* __restrict__ deg, int N)
{
    int n = blockIdx.x * 256 + threadIdx.x;
    if (n < N) deg[n] = 0u;
}

// ---------------- degree over dst (800k int atomics) ----------------
__global__ __launch_bounds__(256)
void deg_kernel(const int* __restrict__ ei, int E, unsigned* __restrict__ deg)
{
    int e = blockIdx.x * 256 + threadIdx.x;
    if (e < E) atomicAdd(&deg[ei[E + e]], 1u);
}

// ---------------- single-block scan: row_start/wofs = exclusive prefix(deg); dinv ----------------
__global__ __launch_bounds__(256)
void scan_kernel(const unsigned* __restrict__ deg, int N,
                 int* __restrict__ row_start, int* __restrict__ wofs,
                 float* __restrict__ dinv)
{
    __shared__ int sums[256];
    const int tid = threadIdx.x;
    const int chunk = (N + 255) / 256;
    const int lo = tid * chunk;
    const int hi = min(lo + chunk, N);
    int s = 0;
    for (int n = lo; n < hi; ++n) s += (int)deg[n];
    sums[tid] = s;
    __syncthreads();
    // Hillis-Steele inclusive scan over 256
    for (int off = 1; off < 256; off <<= 1) {
        int v = 0;
        if (tid >= off) v = sums[tid - off];
        __syncthreads();
        if (tid >= off) sums[tid] += v;
        __syncthreads();
    }
    int run = (tid == 0) ? 0 : sums[tid - 1];  // exclusive base for this chunk
    for (int n = lo; n < hi; ++n) {
        int d = (int)deg[n];
        row_start[n] = run;
        wofs[n] = run;
        dinv[n] = rsqrtf((float)(d + 1));
        run += d;
    }
}

// ---------------- bucket fill: sorted_src grouped by dst ----------------
__global__ __launch_bounds__(256)
void fill_kernel(const int* __restrict__ ei, int E,
                 int* __restrict__ wofs, int* __restrict__ sorted_src)
{
    int e = blockIdx.x * 256 + threadIdx.x;
    if (e < E) {
        int dst = ei[E + e];
        int pos = atomicAdd(&wofs[dst], 1);
        sorted_src[pos] = ei[e];
    }
}

// ---------------- fused gather + self-loop + bias + LSTM gates ----------------
// one wave per node; lane = (batch b = lane>>5, hh = lane&31)
// lane accumulates gate features hh, hh+32, hh+64, hh+96 for batch b.
__global__ __launch_bounds__(256)
void gather_gate_kernel(const int* __restrict__ row_start,
                        const unsigned* __restrict__ deg,
                        const int* __restrict__ sorted_src,
                        const __hip_bfloat16* __restrict__ xw,
                        const float* __restrict__ dinv,
                        const float* __restrict__ bias,
                        const float* __restrict__ c_cur,
                        float* __restrict__ out,   // [h_next | c_next] fp32
                        int N)
{
    const int wid = (int)(((long)blockIdx.x * 256 + threadIdx.x) >> 6);
    if (wid >= N) return;
    const int n = wid;
    const int lane = threadIdx.x & 63;
    const int b = lane >> 5;
    const int hh = lane & 31;

    const int start = row_start[n];
    const int dn = (int)deg[n];

    float acc0 = 0.f, acc1 = 0.f, acc2 = 0.f, acc3 = 0.f;
    const __hip_bfloat16* __restrict__ xwb = xw + ((long)b * N) * G4H + hh;

    for (int base = 0; base < dn; base += 64) {
        int cnt = min(64, dn - base);
        int   s_reg = 0;
        float d_reg = 0.f;
        if (lane < cnt) {
            s_reg = sorted_src[start + base + lane];
            d_reg = dinv[s_reg];
        }
        for (int i = 0; i < cnt; ++i) {
            int   src = __shfl(s_reg, i);
            float dsw = __shfl(d_reg, i);
            const __hip_bfloat16* p = xwb + (long)src * G4H;
            float v0 = bf2f(p[0]);
            float v1 = bf2f(p[32]);
            float v2 = bf2f(p[64]);
            float v3 = bf2f(p[96]);
            acc0 = fmaf(v0, dsw, acc0);
            acc1 = fmaf(v1, dsw, acc1);
            acc2 = fmaf(v2, dsw, acc2);
            acc3 = fmaf(v3, dsw, acc3);
        }
    }

    const float di = dinv[n];
    const __hip_bfloat16* ps = xwb + (long)n * G4H;   // self-loop features
    float cc0 = di * (acc0 + di * bf2f(ps[0]))  + bias[hh];
    float cc1 = di * (acc1 + di * bf2f(ps[32])) + bias[hh + 32];
    float cc2 = di * (acc2 + di * bf2f(ps[64])) + bias[hh + 64];
    float cc3 = di * (acc3 + di * bf2f(ps[96])) + bias[hh + 96];

    float ig = 1.f / (1.f + __expf(-cc0));
    float fg = 1.f / (1.f + __expf(-cc1));
    float og = 1.f / (1.f + __expf(-cc2));
    float gg = tanhf(cc3);

    long t = ((long)b * N + n) * H_DIM + hh;
    float c  = c_cur[t];
    float cn = fmaf(fg, c, ig * gg);
    float hn = og * tanhf(cn);
    out[t]                        = hn;
    out[(long)2 * N * H_DIM + t]  = cn;
}

extern "C" void kernel_launch(void* const* d_in, const int* in_sizes, int n_in,
                              void* d_out, int out_size, void* d_ws, size_t ws_size,
                              hipStream_t stream)
{
    const float* x    = (const float*)d_in[0];
    const int*   ei   = (const int*)d_in[1];
    const float* h    = (const float*)d_in[2];
    const float* c    = (const float*)d_in[3];
    const float* W    = (const float*)d_in[4];
    const float* bias = (const float*)d_in[5];

    const int  E  = in_sizes[1] / 2;                 // 800000
    const long BN = (long)in_sizes[2] / H_DIM;       // B*N = 100000
    const int  B  = 2;
    const int  N  = (int)(BN / B);                   // 50000

    // workspace layout
    char* ws = (char*)d_ws;
    __hip_bfloat16* xw = (__hip_bfloat16*)ws;                       // BN*128 bf16
    size_t off = (size_t)BN * G4H * sizeof(__hip_bfloat16);
    unsigned* deg = (unsigned*)(ws + off);   off += (size_t)N * sizeof(unsigned);
    float* dinv   = (float*)(ws + off);      off += (size_t)N * sizeof(float);
    int* row_start= (int*)(ws + off);        off += (size_t)N * sizeof(int);
    int* wofs     = (int*)(ws + off);        off += (size_t)N * sizeof(int);
    int* sorted_src = (int*)(ws + off);      off += (size_t)E * sizeof(int);

    // 1) GEMM xw = [x|h] @ W
    int gemm_grid = (int)((BN + NPB - 1) / NPB);
    xw_kernel<<<gemm_grid, 128, 0, stream>>>(x, h, W, xw, BN);

    // 2) zero deg
    zero_deg_kernel<<<(N + 255) / 256, 256, 0, stream>>>(deg, N);

    // 3) degree histogram over dst
    deg_kernel<<<(E + 255) / 256, 256, 0, stream>>>(ei, E, deg);

    // 4) scan → row_start, wofs, dinv
    scan_kernel<<<1, 256, 0, stream>>>(deg, N, row_start, wofs, dinv);

    // 5) bucket fill (CSR by dst)
    fill_kernel<<<(E + 255) / 256, 256, 0, stream>>>(ei, E, wofs, sorted_src);

    // 6) fused gather + gates → out
    int gg_grid = (N * 64 + 255) / 256;
    gather_gate_kernel<<<gg_grid, 256, 0, stream>>>(
        row_start, deg, sorted_src, xw, dinv, bias, c, (float*)d_out, N);
}

// Round 5
// 445.811 us; speedup vs baseline: 9.2706x; 3.8633x over previous
//
#include <hip/hip_runtime.h>
#include <hip/hip_bf16.h>

constexpr int G4H   = 128;  // 4*H
constexpr int H_DIM = 32;
constexpr int KPAD  = 104;  // padded k-stride (bf16 elems): 16B-aligned rows, spreads banks

typedef __attribute__((ext_vector_type(8))) short bf16x8;
typedef __attribute__((ext_vector_type(4))) float f32x4;

static __device__ __forceinline__ float bf2f(__hip_bfloat16 v) { return __bfloat162float(v); }
static __device__ __forceinline__ unsigned short f2bf_bits(float v) {
    __hip_bfloat16 b = __float2bfloat16(v);
    return *reinterpret_cast<unsigned short*>(&b);
}

// ---------------- xw = concat(x,h) @ W via MFMA bf16 ----------------
// block = 256 thr = 4 waves; 64 rows/block; A,Wt staged in LDS; 24 MFMAs/wave.
__global__ __launch_bounds__(256)
void xw_kernel(const float* __restrict__ x,
               const float* __restrict__ h,
               const float* __restrict__ W,
               __hip_bfloat16* __restrict__ xw,
               int BN)
{
    __shared__ __align__(16) unsigned short A_lds[64 * KPAD];   // [row][k]
    __shared__ __align__(16) unsigned short Wt[G4H * KPAD];     // [n][k]
    const int t = threadIdx.x;

    // stage W transposed: W[k][n] fp32 -> Wt[n][k] bf16  (12288 elems, 48/thread)
    #pragma unroll 4
    for (int j = 0; j < 48; ++j) {
        int idx = t + 256 * j;
        int k = idx >> 7;
        int n = idx & 127;
        Wt[n * KPAD + k] = f2bf_bits(W[idx]);
    }
    // stage A: rows row0..row0+63 of [x|h] -> bf16  (6144 elems, 24/thread)
    const long row0 = (long)blockIdx.x * 64;
    #pragma unroll 4
    for (int j = 0; j < 24; ++j) {
        int idx = t + 256 * j;
        int r = idx / 96;
        int f = idx - r * 96;
        long bn = row0 + r;
        float v = 0.f;
        if (bn < BN)
            v = (f < 64) ? x[bn * 64 + f] : h[bn * 32 + (f - 64)];
        A_lds[r * KPAD + f] = f2bf_bits(v);
    }
    __syncthreads();

    const int wv   = t >> 6;        // wave id 0..3 -> rows 16*wv..16*wv+15
    const int lane = t & 63;
    const int m    = lane & 15;     // M row within tile (A) / N col (B,D)
    const int q    = lane >> 4;     // quad

    f32x4 acc[8] = {};              // 8 n-tiles of 16 cols
    #pragma unroll
    for (int k0 = 0; k0 < 96; k0 += 32) {
        bf16x8 a = *reinterpret_cast<const bf16x8*>(&A_lds[(wv * 16 + m) * KPAD + k0 + q * 8]);
        #pragma unroll
        for (int nt = 0; nt < 8; ++nt) {
            bf16x8 b = *reinterpret_cast<const bf16x8*>(&Wt[(nt * 16 + m) * KPAD + k0 + q * 8]);
            acc[nt] = __builtin_amdgcn_mfma_f32_16x16x32_bf16(a, b, acc[nt], 0, 0, 0);
        }
    }

    // epilogue: D[row=q*4+r][col=m] per n-tile
    #pragma unroll
    for (int nt = 0; nt < 8; ++nt) {
        #pragma unroll
        for (int r = 0; r < 4; ++r) {
            long gm = row0 + wv * 16 + q * 4 + r;
            if (gm < BN) xw[gm * G4H + nt * 16 + m] = __float2bfloat16(acc[nt][r]);
        }
    }
}

// ---------------- zero deg ----------------
__global__ __launch_bounds__(256)
void zero_deg_kernel(unsigned* __restrict__ deg, int N)
{
    int n = blockIdx.x * 256 + threadIdx.x;
    if (n < N) deg[n] = 0u;
}

// ---------------- degree over dst (800k int atomics) ----------------
__global__ __launch_bounds__(256)
void deg_kernel(const int* __restrict__ ei, int E, unsigned* __restrict__ deg)
{
    int e = blockIdx.x * 256 + threadIdx.x;
    if (e < E) atomicAdd(&deg[ei[E + e]], 1u);
}

// ---------------- single-block scan: row_start/wofs = exclusive prefix(deg); dinv ----------------
__global__ __launch_bounds__(256)
void scan_kernel(const unsigned* __restrict__ deg, int N,
                 int* __restrict__ row_start, int* __restrict__ wofs,
                 float* __restrict__ dinv)
{
    __shared__ int sums[256];
    const int tid = threadIdx.x;
    const int chunk = (N + 255) / 256;
    const int lo = tid * chunk;
    const int hi = min(lo + chunk, N);
    int s = 0;
    for (int n = lo; n < hi; ++n) s += (int)deg[n];
    sums[tid] = s;
    __syncthreads();
    for (int off = 1; off < 256; off <<= 1) {
        int v = 0;
        if (tid >= off) v = sums[tid - off];
        __syncthreads();
        if (tid >= off) sums[tid] += v;
        __syncthreads();
    }
    int run = (tid == 0) ? 0 : sums[tid - 1];
    for (int n = lo; n < hi; ++n) {
        int d = (int)deg[n];
        row_start[n] = run;
        wofs[n] = run;
        dinv[n] = rsqrtf((float)(d + 1));
        run += d;
    }
}

// ---------------- bucket fill: sorted_src grouped by dst ----------------
__global__ __launch_bounds__(256)
void fill_kernel(const int* __restrict__ ei, int E,
                 int* __restrict__ wofs, int* __restrict__ sorted_src)
{
    int e = blockIdx.x * 256 + threadIdx.x;
    if (e < E) {
        int dst = ei[E + e];
        int pos = atomicAdd(&wofs[dst], 1);
        sorted_src[pos] = ei[e];
    }
}

// ---------------- fused gather + self-loop + bias + LSTM gates ----------------
__global__ __launch_bounds__(256)
void gather_gate_kernel(const int* __restrict__ row_start,
                        const unsigned* __restrict__ deg,
                        const int* __restrict__ sorted_src,
                        const __hip_bfloat16* __restrict__ xw,
                        const float* __restrict__ dinv,
                        const float* __restrict__ bias,
                        const float* __restrict__ c_cur,
                        float* __restrict__ out,   // [h_next | c_next] fp32
                        int N)
{
    const int wid = (int)(((long)blockIdx.x * 256 + threadIdx.x) >> 6);
    if (wid >= N) return;
    const int n = wid;
    const int lane = threadIdx.x & 63;
    const int b = lane >> 5;
    const int hh = lane & 31;

    const int start = row_start[n];
    const int dn = (int)deg[n];

    float acc0 = 0.f, acc1 = 0.f, acc2 = 0.f, acc3 = 0.f;
    const __hip_bfloat16* __restrict__ xwb = xw + ((long)b * N) * G4H + hh;

    for (int base = 0; base < dn; base += 64) {
        int cnt = min(64, dn - base);
        int   s_reg = 0;
        float d_reg = 0.f;
        if (lane < cnt) {
            s_reg = sorted_src[start + base + lane];
            d_reg = dinv[s_reg];
        }
        for (int i = 0; i < cnt; ++i) {
            int   src = __shfl(s_reg, i);
            float dsw = __shfl(d_reg, i);
            const __hip_bfloat16* p = xwb + (long)src * G4H;
            float v0 = bf2f(p[0]);
            float v1 = bf2f(p[32]);
            float v2 = bf2f(p[64]);
            float v3 = bf2f(p[96]);
            acc0 = fmaf(v0, dsw, acc0);
            acc1 = fmaf(v1, dsw, acc1);
            acc2 = fmaf(v2, dsw, acc2);
            acc3 = fmaf(v3, dsw, acc3);
        }
    }

    const float di = dinv[n];
    const __hip_bfloat16* ps = xwb + (long)n * G4H;   // self-loop features
    float cc0 = di * (acc0 + di * bf2f(ps[0]))  + bias[hh];
    float cc1 = di * (acc1 + di * bf2f(ps[32])) + bias[hh + 32];
    float cc2 = di * (acc2 + di * bf2f(ps[64])) + bias[hh + 64];
    float cc3 = di * (acc3 + di * bf2f(ps[96])) + bias[hh + 96];

    float ig = 1.f / (1.f + __expf(-cc0));
    float fg = 1.f / (1.f + __expf(-cc1));
    float og = 1.f / (1.f + __expf(-cc2));
    float gg = tanhf(cc3);

    long t = ((long)b * N + n) * H_DIM + hh;
    float c  = c_cur[t];
    float cn = fmaf(fg, c, ig * gg);
    float hn = og * tanhf(cn);
    out[t]                        = hn;
    out[(long)2 * N * H_DIM + t]  = cn;
}

extern "C" void kernel_launch(void* const* d_in, const int* in_sizes, int n_in,
                              void* d_out, int out_size, void* d_ws, size_t ws_size,
                              hipStream_t stream)
{
    const float* x    = (const float*)d_in[0];
    const int*   ei   = (const int*)d_in[1];
    const float* h    = (const float*)d_in[2];
    const float* c    = (const float*)d_in[3];
    const float* W    = (const float*)d_in[4];
    const float* bias = (const float*)d_in[5];

    const int  E  = in_sizes[1] / 2;                 // 800000
    const long BN = (long)in_sizes[2] / H_DIM;       // B*N = 100000
    const int  B  = 2;
    const int  N  = (int)(BN / B);                   // 50000

    // workspace layout
    char* ws = (char*)d_ws;
    __hip_bfloat16* xw = (__hip_bfloat16*)ws;                       // BN*128 bf16
    size_t off = (size_t)BN * G4H * sizeof(__hip_bfloat16);
    unsigned* deg = (unsigned*)(ws + off);   off += (size_t)N * sizeof(unsigned);
    float* dinv   = (float*)(ws + off);      off += (size_t)N * sizeof(float);
    int* row_start= (int*)(ws + off);        off += (size_t)N * sizeof(int);
    int* wofs     = (int*)(ws + off);        off += (size_t)N * sizeof(int);
    int* sorted_src = (int*)(ws + off);      off += (size_t)E * sizeof(int);

    // 1) MFMA GEMM xw = [x|h] @ W
    int gemm_grid = (int)((BN + 63) / 64);
    xw_kernel<<<gemm_grid, 256, 0, stream>>>(x, h, W, xw, (int)BN);

    // 2) zero deg
    zero_deg_kernel<<<(N + 255) / 256, 256, 0, stream>>>(deg, N);

    // 3) degree histogram over dst
    deg_kernel<<<(E + 255) / 256, 256, 0, stream>>>(ei, E, deg);

    // 4) scan → row_start, wofs, dinv
    scan_kernel<<<1, 256, 0, stream>>>(deg, N, row_start, wofs, dinv);

    // 5) bucket fill (CSR by dst)
    fill_kernel<<<(E + 255) / 256, 256, 0, stream>>>(ei, E, wofs, sorted_src);

    // 6) fused gather + gates → out
    int gg_grid = (N * 64 + 255) / 256;
    gather_gate_kernel<<<gg_grid, 256, 0, stream>>>(
        row_start, deg, sorted_src, xw, dinv, bias, c, (float*)d_out, N);
}

// Round 6
// 304.606 us; speedup vs baseline: 13.5682x; 1.4636x over previous
//
#include <hip/hip_runtime.h>
#include <hip/hip_bf16.h>

constexpr int G4H   = 128;  // 4*H
constexpr int H_DIM = 32;
constexpr int KPAD  = 104;  // padded k-stride (bf16 elems): 16B-aligned rows, spreads banks

typedef __attribute__((ext_vector_type(8))) short bf16x8;
typedef __attribute__((ext_vector_type(4))) float f32x4;

static __device__ __forceinline__ float bf2f(__hip_bfloat16 v) { return __bfloat162float(v); }
static __device__ __forceinline__ unsigned short f2bf_bits(float v) {
    __hip_bfloat16 b = __float2bfloat16(v);
    return *reinterpret_cast<unsigned short*>(&b);
}

// ---------------- xw = concat(x,h) @ W via MFMA bf16 ----------------
__global__ __launch_bounds__(256)
void xw_kernel(const float* __restrict__ x,
               const float* __restrict__ h,
               const float* __restrict__ W,
               __hip_bfloat16* __restrict__ xw,
               int BN)
{
    __shared__ __align__(16) unsigned short A_lds[64 * KPAD];   // [row][k]
    __shared__ __align__(16) unsigned short Wt[G4H * KPAD];     // [n][k]
    const int t = threadIdx.x;

    // stage W transposed: W[k][n] fp32 -> Wt[n][k] bf16  (12288 elems, 48/thread)
    #pragma unroll 4
    for (int j = 0; j < 48; ++j) {
        int idx = t + 256 * j;
        int k = idx >> 7;
        int n = idx & 127;
        Wt[n * KPAD + k] = f2bf_bits(W[idx]);
    }
    // stage A: rows row0..row0+63 of [x|h] -> bf16  (6144 elems, 24/thread)
    const long row0 = (long)blockIdx.x * 64;
    #pragma unroll 4
    for (int j = 0; j < 24; ++j) {
        int idx = t + 256 * j;
        int r = idx / 96;
        int f = idx - r * 96;
        long bn = row0 + r;
        float v = 0.f;
        if (bn < BN)
            v = (f < 64) ? x[bn * 64 + f] : h[bn * 32 + (f - 64)];
        A_lds[r * KPAD + f] = f2bf_bits(v);
    }
    __syncthreads();

    const int wv   = t >> 6;        // wave id 0..3 -> rows 16*wv..16*wv+15
    const int lane = t & 63;
    const int m    = lane & 15;
    const int q    = lane >> 4;

    f32x4 acc[8] = {};
    #pragma unroll
    for (int k0 = 0; k0 < 96; k0 += 32) {
        bf16x8 a = *reinterpret_cast<const bf16x8*>(&A_lds[(wv * 16 + m) * KPAD + k0 + q * 8]);
        #pragma unroll
        for (int nt = 0; nt < 8; ++nt) {
            bf16x8 b = *reinterpret_cast<const bf16x8*>(&Wt[(nt * 16 + m) * KPAD + k0 + q * 8]);
            acc[nt] = __builtin_amdgcn_mfma_f32_16x16x32_bf16(a, b, acc[nt], 0, 0, 0);
        }
    }

    #pragma unroll
    for (int nt = 0; nt < 8; ++nt) {
        #pragma unroll
        for (int r = 0; r < 4; ++r) {
            long gm = row0 + wv * 16 + q * 4 + r;
            if (gm < BN) xw[gm * G4H + nt * 16 + m] = __float2bfloat16(acc[nt][r]);
        }
    }
}

// ---------------- zero deg ----------------
__global__ __launch_bounds__(256)
void zero_deg_kernel(unsigned* __restrict__ deg, int N)
{
    int n = blockIdx.x * 256 + threadIdx.x;
    if (n < N) deg[n] = 0u;
}

// ---------------- degree over dst (800k int atomics) ----------------
__global__ __launch_bounds__(256)
void deg_kernel(const int* __restrict__ ei, int E, unsigned* __restrict__ deg)
{
    int e = blockIdx.x * 256 + threadIdx.x;
    if (e < E) atomicAdd(&deg[ei[E + e]], 1u);
}

// ---------------- 3-phase device-wide exclusive scan over deg ----------------
// Phase A: per-block (256 elems) reduction -> partials[b]
__global__ __launch_bounds__(256)
void scan_partial_kernel(const unsigned* __restrict__ deg, int N,
                         int* __restrict__ partials)
{
    __shared__ int red[256];
    int n = blockIdx.x * 256 + threadIdx.x;
    red[threadIdx.x] = (n < N) ? (int)deg[n] : 0;
    __syncthreads();
    #pragma unroll
    for (int s = 128; s > 0; s >>= 1) {
        if (threadIdx.x < s) red[threadIdx.x] += red[threadIdx.x + s];
        __syncthreads();
    }
    if (threadIdx.x == 0) partials[blockIdx.x] = red[0];
}

// Phase B: one block scans NB (<=2048) partials -> exclusive block offsets
__global__ __launch_bounds__(256)
void scan_offsets_kernel(int* __restrict__ partials, int NB)
{
    __shared__ int sums[256];
    const int tid = threadIdx.x;
    const int chunk = (NB + 255) / 256;   // <=8
    const int lo = tid * chunk;
    const int hi = min(lo + chunk, NB);
    int local[8];
    int s = 0;
    for (int i = lo; i < hi; ++i) { local[i - lo] = partials[i]; s += local[i - lo]; }
    sums[tid] = s;
    __syncthreads();
    for (int off = 1; off < 256; off <<= 1) {
        int v = 0;
        if (tid >= off) v = sums[tid - off];
        __syncthreads();
        if (tid >= off) sums[tid] += v;
        __syncthreads();
    }
    int run = (tid == 0) ? 0 : sums[tid - 1];
    for (int i = lo; i < hi; ++i) { int d = local[i - lo]; partials[i] = run; run += d; }
}

// Phase C: per-block exclusive scan + block offset -> row_start/wofs/dinv
__global__ __launch_bounds__(256)
void scan_write_kernel(const unsigned* __restrict__ deg, int N,
                       const int* __restrict__ partials,
                       int* __restrict__ row_start, int* __restrict__ wofs,
                       float* __restrict__ dinv)
{
    __shared__ int sums[256];
    const int tid = threadIdx.x;
    int n = blockIdx.x * 256 + tid;
    int d = (n < N) ? (int)deg[n] : 0;
    sums[tid] = d;
    __syncthreads();
    for (int off = 1; off < 256; off <<= 1) {
        int v = 0;
        if (tid >= off) v = sums[tid - off];
        __syncthreads();
        if (tid >= off) sums[tid] += v;
        __syncthreads();
    }
    if (n < N) {
        int excl = sums[tid] - d + partials[blockIdx.x];
        row_start[n] = excl;
        wofs[n] = excl;
        dinv[n] = rsqrtf((float)(d + 1));
    }
}

// ---------------- bucket fill: sorted_src grouped by dst ----------------
__global__ __launch_bounds__(256)
void fill_kernel(const int* __restrict__ ei, int E,
                 int* __restrict__ wofs, int* __restrict__ sorted_src)
{
    int e = blockIdx.x * 256 + threadIdx.x;
    if (e < E) {
        int dst = ei[E + e];
        int pos = atomicAdd(&wofs[dst], 1);
        sorted_src[pos] = ei[e];
    }
}

// ---------------- fused gather + self-loop + bias + LSTM gates ----------------
__global__ __launch_bounds__(256)
void gather_gate_kernel(const int* __restrict__ row_start,
                        const unsigned* __restrict__ deg,
                        const int* __restrict__ sorted_src,
                        const __hip_bfloat16* __restrict__ xw,
                        const float* __restrict__ dinv,
                        const float* __restrict__ bias,
                        const float* __restrict__ c_cur,
                        float* __restrict__ out,   // [h_next | c_next] fp32
                        int N)
{
    const int wid = (int)(((long)blockIdx.x * 256 + threadIdx.x) >> 6);
    if (wid >= N) return;
    const int n = wid;
    const int lane = threadIdx.x & 63;
    const int b = lane >> 5;
    const int hh = lane & 31;

    const int start = row_start[n];
    const int dn = (int)deg[n];

    float acc0 = 0.f, acc1 = 0.f, acc2 = 0.f, acc3 = 0.f;
    const __hip_bfloat16* __restrict__ xwb = xw + ((long)b * N) * G4H + hh;

    for (int base = 0; base < dn; base += 64) {
        int cnt = min(64, dn - base);
        int   s_reg = 0;
        float d_reg = 0.f;
        if (lane < cnt) {
            s_reg = sorted_src[start + base + lane];
            d_reg = dinv[s_reg];
        }
        for (int i = 0; i < cnt; ++i) {
            int   src = __shfl(s_reg, i);
            float dsw = __shfl(d_reg, i);
            const __hip_bfloat16* p = xwb + (long)src * G4H;
            float v0 = bf2f(p[0]);
            float v1 = bf2f(p[32]);
            float v2 = bf2f(p[64]);
            float v3 = bf2f(p[96]);
            acc0 = fmaf(v0, dsw, acc0);
            acc1 = fmaf(v1, dsw, acc1);
            acc2 = fmaf(v2, dsw, acc2);
            acc3 = fmaf(v3, dsw, acc3);
        }
    }

    const float di = dinv[n];
    const __hip_bfloat16* ps = xwb + (long)n * G4H;   // self-loop features
    float cc0 = di * (acc0 + di * bf2f(ps[0]))  + bias[hh];
    float cc1 = di * (acc1 + di * bf2f(ps[32])) + bias[hh + 32];
    float cc2 = di * (acc2 + di * bf2f(ps[64])) + bias[hh + 64];
    float cc3 = di * (acc3 + di * bf2f(ps[96])) + bias[hh + 96];

    float ig = 1.f / (1.f + __expf(-cc0));
    float fg = 1.f / (1.f + __expf(-cc1));
    float og = 1.f / (1.f + __expf(-cc2));
    float gg = tanhf(cc3);

    long t = ((long)b * N + n) * H_DIM + hh;
    float c  = c_cur[t];
    float cn = fmaf(fg, c, ig * gg);
    float hn = og * tanhf(cn);
    out[t]                        = hn;
    out[(long)2 * N * H_DIM + t]  = cn;
}

extern "C" void kernel_launch(void* const* d_in, const int* in_sizes, int n_in,
                              void* d_out, int out_size, void* d_ws, size_t ws_size,
                              hipStream_t stream)
{
    const float* x    = (const float*)d_in[0];
    const int*   ei   = (const int*)d_in[1];
    const float* h    = (const float*)d_in[2];
    const float* c    = (const float*)d_in[3];
    const float* W    = (const float*)d_in[4];
    const float* bias = (const float*)d_in[5];

    const int  E  = in_sizes[1] / 2;                 // 800000
    const long BN = (long)in_sizes[2] / H_DIM;       // B*N = 100000
    const int  B  = 2;
    const int  N  = (int)(BN / B);                   // 50000

    // workspace layout
    char* ws = (char*)d_ws;
    __hip_bfloat16* xw = (__hip_bfloat16*)ws;                       // BN*128 bf16
    size_t off = (size_t)BN * G4H * sizeof(__hip_bfloat16);
    unsigned* deg = (unsigned*)(ws + off);   off += (size_t)N * sizeof(unsigned);
    float* dinv   = (float*)(ws + off);      off += (size_t)N * sizeof(float);
    int* row_start= (int*)(ws + off);        off += (size_t)N * sizeof(int);
    int* wofs     = (int*)(ws + off);        off += (size_t)N * sizeof(int);
    int* sorted_src = (int*)(ws + off);      off += (size_t)E * sizeof(int);
    int NB = (N + 255) / 256;
    int* partials = (int*)(ws + off);        off += (size_t)NB * sizeof(int);

    // 1) MFMA GEMM xw = [x|h] @ W
    int gemm_grid = (int)((BN + 63) / 64);
    xw_kernel<<<gemm_grid, 256, 0, stream>>>(x, h, W, xw, (int)BN);

    // 2) zero deg
    zero_deg_kernel<<<(N + 255) / 256, 256, 0, stream>>>(deg, N);

    // 3) degree histogram over dst
    deg_kernel<<<(E + 255) / 256, 256, 0, stream>>>(ei, E, deg);

    // 4) device-wide exclusive scan (3 phases) → row_start, wofs, dinv
    scan_partial_kernel<<<NB, 256, 0, stream>>>(deg, N, partials);
    scan_offsets_kernel<<<1, 256, 0, stream>>>(partials, NB);
    scan_write_kernel<<<NB, 256, 0, stream>>>(deg, N, partials, row_start, wofs, dinv);

    // 5) bucket fill (CSR by dst)
    fill_kernel<<<(E + 255) / 256, 256, 0, stream>>>(ei, E, wofs, sorted_src);

    // 6) fused gather + gates → out
    int gg_grid = (N * 64 + 255) / 256;
    gather_gate_kernel<<<gg_grid, 256, 0, stream>>>(
        row_start, deg, sorted_src, xw, dinv, bias, c, (float*)d_out, N);
}